// Round 1
// baseline (895.686 us; speedup 1.0000x reference)
//
#include <hip/hip_runtime.h>

#define R_ET 8
#define DH 128

typedef __bf16 bf16x8 __attribute__((ext_vector_type(8)));
typedef float f32x4 __attribute__((ext_vector_type(4)));

__device__ __forceinline__ ushort f2bf(float f) {
  unsigned u = __float_as_uint(f);
  u += 0x7fff + ((u >> 16) & 1);  // round-to-nearest-even
  return (ushort)(u >> 16);
}

// Swizzled activation/weight layout: element (row, k) lives at
//   row*128 + ((k>>3) ^ (row&7))*8 + (k&7)
// so the flat global_load_lds image gives conflict-free (2-way) b128 fragment reads.

// ---------------- degree count per (dst, etype) ----------------
__global__ void count_kernel(const int* __restrict__ ei, const int* __restrict__ et,
                             int* __restrict__ cnt, int E) {
  int e = blockIdx.x * blockDim.x + threadIdx.x;
  if (e < E) atomicAdd(&cnt[ei[E + e] * R_ET + et[e]], 1);
}

// ---------------- 3-phase device-wide exclusive scan of per-node degree ----------------
__global__ __launch_bounds__(1024) void scan1_kernel(const int* __restrict__ cnt,
                                                     int* __restrict__ off,
                                                     int* __restrict__ bsum, int N) {
  __shared__ int s[1024];
  int tid = threadIdx.x;
  int node = blockIdx.x * 1024 + tid;
  int d = 0;
  if (node < N) {
    const int4* c = (const int4*)&cnt[node * R_ET];
    int4 a = c[0], b = c[1];
    d = a.x + a.y + a.z + a.w + b.x + b.y + b.z + b.w;
  }
  s[tid] = d;
  __syncthreads();
  for (int step = 1; step < 1024; step <<= 1) {
    int v = (tid >= step) ? s[tid - step] : 0;
    __syncthreads();
    s[tid] += v;
    __syncthreads();
  }
  if (node < N) off[node] = s[tid] - d;
  if (tid == 1023) bsum[blockIdx.x] = s[1023];
}

__global__ __launch_bounds__(1024) void scan2_kernel(int* __restrict__ bsum, int nb) {
  __shared__ int s[1024];
  int tid = threadIdx.x;
  int v = (tid < nb) ? bsum[tid] : 0;
  s[tid] = v;
  __syncthreads();
  for (int step = 1; step < 1024; step <<= 1) {
    int x = (tid >= step) ? s[tid - step] : 0;
    __syncthreads();
    s[tid] += x;
    __syncthreads();
  }
  if (tid < nb) bsum[tid] = s[tid] - v;
}

__global__ __launch_bounds__(1024) void scan3_kernel(int* __restrict__ off,
                                                     int* __restrict__ cursor,
                                                     const int* __restrict__ bsum,
                                                     int N, int E) {
  int node = blockIdx.x * 1024 + threadIdx.x;
  if (node < N) {
    int o = off[node] + bsum[blockIdx.x];
    off[node] = o;
    cursor[node] = o;
  }
  if (node == 0) off[N] = E;
}

// ---------------- place edges into dst-sorted slots (packed metadata) ----------------
__global__ void place_kernel(const int* __restrict__ ei, const int* __restrict__ et,
                             const int* __restrict__ cnt, int* __restrict__ cursor,
                             int2* __restrict__ meta, int E) {
  int e = blockIdx.x * blockDim.x + threadIdx.x;
  if (e >= E) return;
  int src = ei[e], dst = ei[E + e], r = et[e];
  int slot = atomicAdd(&cursor[dst], 1);
  meta[slot] = make_int2(src | (r << 28),
                         __float_as_int(1.f / (float)cnt[dst * R_ET + r]));
}

// ---------------- weight convert+transpose: Wt[mat][n][k] bf16, swizzled ----------------
__global__ __launch_bounds__(256) void wconv_kernel(const float* __restrict__ root,
                                                    const float* __restrict__ W,
                                                    ushort* __restrict__ Wt) {
  int mat = blockIdx.x;  // 0 = root, 1..8 = W[r]
  const float* src = (mat == 0) ? root : (W + (size_t)(mat - 1) * DH * DH);
  ushort* dst = Wt + (size_t)mat * DH * DH;
  for (int idx = threadIdx.x; idx < DH * DH; idx += 256) {
    int n = idx >> 7, k = idx & 127;
    dst[n * DH + (((k >> 3) ^ (n & 7)) << 3) + (k & 7)] = f2bf(src[k * DH + n]);
  }
}

// ---------------- activation convert (layer 0), zero-pads rows, swizzled ----------------
__global__ __launch_bounds__(256) void aconv_kernel(const float* __restrict__ src,
                                                    ushort* __restrict__ dst,
                                                    int total, int padtotal) {
  int i4 = (blockIdx.x * 256 + threadIdx.x) * 4;
  if (i4 >= padtotal) return;
  int row = i4 >> 7, k = i4 & 127;
  ushort4 o = make_ushort4(0, 0, 0, 0);
  if (i4 < total) {
    float4 v = *(const float4*)&src[i4];
    o = make_ushort4(f2bf(v.x), f2bf(v.y), f2bf(v.z), f2bf(v.w));
  }
  *(ushort4*)&dst[(size_t)row * DH + (((k >> 3) ^ (row & 7)) << 3) + (k & 7)] = o;
}

// ---------------- bf16 MFMA GEMM, 3 matrices per block ----------------
// grid (Npad/128, 3); block y handles mats {3y, 3y+1, 3y+2}; mat 0 -> y (fp32+bias),
// mats 1..8 -> t slab mat-1 (bf16, plain row-major). A tile staged once, reused 3x.
// MFMA operands are SWAPPED (mfma(B,A)) so each lane's 4 acc regs are 4 consecutive
// feature columns of ONE node row -> vectorized 8B/16B epilogue stores (4x fewer
// store instructions than the scalar layout). Next mat's B-stage is issued before
// the epilogue so staging latency hides under the stores.
__global__ __launch_bounds__(256) void gemm_mfma(
    const ushort* __restrict__ Abf, const ushort* __restrict__ Wt,
    const float* __restrict__ bias, float* __restrict__ y,
    ushort* __restrict__ t, int N) {
  __shared__ ushort As[128 * DH];  // 32 KB, swizzled image (flat copy of Abf tile)
  __shared__ ushort Bs[128 * DH];  // 32 KB, swizzled image of Wt[mat]
  const int tid = threadIdx.x;
  const int wave = tid >> 6, lane = tid & 63;
  const int quad = lane >> 4, l15 = lane & 15;
  const int rbase = blockIdx.x * 128;
  const int wr = (wave >> 1) * 64, wc = (wave & 1) * 64;

  const ushort* gA = Abf + (size_t)rbase * DH;
#pragma unroll
  for (int it = 0; it < 8; it++) {
    __builtin_amdgcn_global_load_lds(
        (const __attribute__((address_space(1))) void*)(gA + (it * 256 + tid) * 8),
        (__attribute__((address_space(3))) void*)(As + (it * 256 + wave * 64) * 8), 16, 0, 0);
  }
  {
    const ushort* gB = Wt + (size_t)(blockIdx.y * 3) * DH * DH;
#pragma unroll
    for (int it = 0; it < 8; it++) {
      __builtin_amdgcn_global_load_lds(
          (const __attribute__((address_space(1))) void*)(gB + (it * 256 + tid) * 8),
          (__attribute__((address_space(3))) void*)(Bs + (it * 256 + wave * 64) * 8), 16, 0, 0);
    }
  }

  for (int m = 0; m < 3; m++) {
    const int mat = blockIdx.y * 3 + m;
    __syncthreads();  // staged A (first iter) + B(mat) visible to all waves

    f32x4 acc[4][4];
#pragma unroll
    for (int i = 0; i < 4; i++)
#pragma unroll
      for (int j = 0; j < 4; j++) acc[i][j] = (f32x4){0.f, 0.f, 0.f, 0.f};

#pragma unroll
    for (int kc = 0; kc < 4; kc++) {
      bf16x8 af[4], bfr[4];
#pragma unroll
      for (int i = 0; i < 4; i++) {
        int ra = wr + i * 16 + l15;
        int rb = wc + i * 16 + l15;
        af[i] = *(const bf16x8*)&As[ra * DH + (((kc * 4 + quad) ^ (ra & 7)) << 3)];
        bfr[i] = *(const bf16x8*)&Bs[rb * DH + (((kc * 4 + quad) ^ (rb & 7)) << 3)];
      }
#pragma unroll
      for (int i = 0; i < 4; i++)
#pragma unroll
        for (int j = 0; j < 4; j++)
          acc[i][j] = __builtin_amdgcn_mfma_f32_16x16x32_bf16(bfr[j], af[i], acc[i][j], 0, 0, 0);
    }

    if (m < 2) {
      __syncthreads();  // all waves done reading Bs for this mat
      const ushort* gB = Wt + (size_t)(mat + 1) * DH * DH;
#pragma unroll
      for (int it = 0; it < 8; it++) {
        __builtin_amdgcn_global_load_lds(
            (const __attribute__((address_space(1))) void*)(gB + (it * 256 + tid) * 8),
            (__attribute__((address_space(3))) void*)(Bs + (it * 256 + wave * 64) * 8), 16, 0, 0);
      }
    }

    // Epilogue: swapped-operand D layout -> lane l15 = node row (from af[i]),
    // quad*4 + reg = feature column (from bfr[j]).
    if (mat == 0) {
#pragma unroll
      for (int i = 0; i < 4; i++) {
        int node = rbase + wr + i * 16 + l15;
        if (node < N) {
#pragma unroll
          for (int j = 0; j < 4; j++) {
            int c0 = wc + j * 16 + quad * 4;
            float4 bv = *(const float4*)&bias[c0];
            float4 v = make_float4(acc[i][j][0] + bv.x, acc[i][j][1] + bv.y,
                                   acc[i][j][2] + bv.z, acc[i][j][3] + bv.w);
            *(float4*)&y[(size_t)node * DH + c0] = v;
          }
        }
      }
    } else {
      ushort* tp = t + (size_t)(mat - 1) * (size_t)N * DH;
#pragma unroll
      for (int i = 0; i < 4; i++) {
        int node = rbase + wr + i * 16 + l15;
        if (node < N) {
#pragma unroll
          for (int j = 0; j < 4; j++) {
            int c0 = wc + j * 16 + quad * 4;
            unsigned lo = (unsigned)f2bf(acc[i][j][0]) | ((unsigned)f2bf(acc[i][j][1]) << 16);
            unsigned hi = (unsigned)f2bf(acc[i][j][2]) | ((unsigned)f2bf(acc[i][j][3]) << 16);
            *(uint2*)&tp[(size_t)node * DH + c0] = make_uint2(lo, hi);
          }
        }
      }
    }
  }
}

// ---------------- gather core: accumulate messages for one dst (wave-wide) ----------
__device__ __forceinline__ void gather_accum(const int2* __restrict__ meta,
                                             const ushort* __restrict__ t,
                                             int start, int end, int lane, int N,
                                             float& ax, float& ay) {
  const int colb = lane * 2;
  for (int base = start; base < end; base += 64) {
    int m = min(64, end - base);
    int2 md = make_int2(0, 0);
    if (lane < m) md = meta[base + lane];
    int j = 0;
    for (; j + 4 <= m; j += 4) {
      int p0 = __shfl(md.x, j),     q0 = __shfl(md.y, j);
      int p1 = __shfl(md.x, j + 1), q1 = __shfl(md.y, j + 1);
      int p2 = __shfl(md.x, j + 2), q2 = __shfl(md.y, j + 2);
      int p3 = __shfl(md.x, j + 3), q3 = __shfl(md.y, j + 3);
      unsigned u0 = *(const unsigned*)&t[(((size_t)((unsigned)p0 >> 28) * N + (p0 & 0x0fffffff)) << 7) + colb];
      unsigned u1 = *(const unsigned*)&t[(((size_t)((unsigned)p1 >> 28) * N + (p1 & 0x0fffffff)) << 7) + colb];
      unsigned u2 = *(const unsigned*)&t[(((size_t)((unsigned)p2 >> 28) * N + (p2 & 0x0fffffff)) << 7) + colb];
      unsigned u3 = *(const unsigned*)&t[(((size_t)((unsigned)p3 >> 28) * N + (p3 & 0x0fffffff)) << 7) + colb];
      float s0 = __int_as_float(q0), s1 = __int_as_float(q1);
      float s2 = __int_as_float(q2), s3 = __int_as_float(q3);
      ax = fmaf(__uint_as_float(u0 << 16), s0, ax);
      ay = fmaf(__uint_as_float(u0 & 0xffff0000u), s0, ay);
      ax = fmaf(__uint_as_float(u1 << 16), s1, ax);
      ay = fmaf(__uint_as_float(u1 & 0xffff0000u), s1, ay);
      ax = fmaf(__uint_as_float(u2 << 16), s2, ax);
      ay = fmaf(__uint_as_float(u2 & 0xffff0000u), s2, ay);
      ax = fmaf(__uint_as_float(u3 << 16), s3, ax);
      ay = fmaf(__uint_as_float(u3 & 0xffff0000u), s3, ay);
    }
    for (; j < m; j++) {
      int pj = __shfl(md.x, j);
      float sj = __int_as_float(__shfl(md.y, j));
      unsigned u = *(const unsigned*)&t[(((size_t)((unsigned)pj >> 28) * N + (pj & 0x0fffffff)) << 7) + colb];
      ax = fmaf(__uint_as_float(u << 16), sj, ax);
      ay = fmaf(__uint_as_float(u & 0xffff0000u), sj, ay);
    }
  }
}

// ---------------- CSR gather (layers 0,1): Abf = bf16(relu(y + msgs)), swizzled ------
__global__ __launch_bounds__(256) void gather_mid(
    const int* __restrict__ off, const int2* __restrict__ meta,
    const ushort* __restrict__ t, const float* __restrict__ y,
    ushort* __restrict__ Abf, int N) {
  int dst = blockIdx.x * 4 + (threadIdx.x >> 6);
  if (dst >= N) return;
  int lane = threadIdx.x & 63;
  float ax = 0.f, ay = 0.f;
  gather_accum(meta, t, off[dst], off[dst + 1], lane, N, ax, ay);
  float2 yv = *(const float2*)&y[(size_t)dst * DH + lane * 2];
  float rx = fmaxf(yv.x + ax, 0.f);
  float ry = fmaxf(yv.y + ay, 0.f);
  unsigned o = (unsigned)f2bf(rx) | ((unsigned)f2bf(ry) << 16);
  int k = lane * 2;
  *(unsigned*)&Abf[(size_t)dst * DH + (((k >> 3) ^ (dst & 7)) << 3) + (k & 7)] = o;
}

// ---------------- CSR gather (layer 2): y += msgs (fp32, no relu) ----------------
__global__ __launch_bounds__(256) void gather_last(
    const int* __restrict__ off, const int2* __restrict__ meta,
    const ushort* __restrict__ t, float* __restrict__ y, int N) {
  int dst = blockIdx.x * 4 + (threadIdx.x >> 6);
  if (dst >= N) return;
  int lane = threadIdx.x & 63;
  float ax = 0.f, ay = 0.f;
  gather_accum(meta, t, off[dst], off[dst + 1], lane, N, ax, ay);
  float2* yp = (float2*)&y[(size_t)dst * DH + lane * 2];
  float2 yv = *yp;
  yv.x += ax;
  yv.y += ay;
  *yp = yv;
}

// ---------------- column sums for mean pool ----------------
__global__ __launch_bounds__(256) void pool_kernel(const float* __restrict__ y,
                                                   float* __restrict__ u, int N) {
  __shared__ float s[256];
  int tid = threadIdx.x;
  int c = tid & 127, rr = tid >> 7;
  int n0 = blockIdx.x * 100;
  int nend = min(n0 + 100, N);
  float sum = 0.f;
  for (int n = n0 + rr; n < nend; n += 2) sum += y[(size_t)n * DH + c];
  s[tid] = sum;
  __syncthreads();
  if (tid < 128) atomicAdd(&u[c], s[tid] + s[tid + 128]);
}

// ---------------- final MLP on concat(u1,u2)/N ----------------
__global__ __launch_bounds__(256) void mlp_kernel(
    const float* __restrict__ u, const float* __restrict__ fc1w,
    const float* __restrict__ fc1b, const float* __restrict__ fc2w,
    const float* __restrict__ fc2b, float* __restrict__ out, int N) {
  __shared__ float uin[256];
  __shared__ float hred[128];
  int tid = threadIdx.x;
  uin[tid] = u[tid] * (1.f / (float)N);
  __syncthreads();
  if (tid < 128) {
    float s = fc1b[tid];
    for (int i = 0; i < 256; i++) s = fmaf(uin[i], fc1w[i * 128 + tid], s);
    s = fmaxf(s, 0.f);
    hred[tid] = s * fc2w[tid];
  }
  __syncthreads();
  if (tid == 0) {
    float s = fc2b[0];
    for (int i = 0; i < 128; i++) s += hred[i];
    out[0] = s;
  }
}

extern "C" void kernel_launch(void* const* d_in, const int* in_sizes, int n_in,
                              void* d_out, int out_size, void* d_ws, size_t ws_size,
                              hipStream_t stream) {
  const float* x[2] = {(const float*)d_in[0], (const float*)d_in[3]};
  const int* ei[2] = {(const int*)d_in[1], (const int*)d_in[4]};
  const int* et[2] = {(const int*)d_in[2], (const int*)d_in[5]};
  const float* Wp[3] = {(const float*)d_in[6], (const float*)d_in[9], (const float*)d_in[12]};
  const float* rootp[3] = {(const float*)d_in[7], (const float*)d_in[10], (const float*)d_in[13]};
  const float* biasp[3] = {(const float*)d_in[8], (const float*)d_in[11], (const float*)d_in[14]};
  const float* fc1w = (const float*)d_in[15];
  const float* fc1b = (const float*)d_in[16];
  const float* fc2w = (const float*)d_in[17];
  const float* fc2b = (const float*)d_in[18];

  const int N = in_sizes[0] / DH;
  const int E = in_sizes[2];
  const int Npad = (N + 127) & ~127;
  const int NB = (N + 1023) / 1024;

  char* ws = (char*)d_ws;
  size_t ob = 0;
  auto alloc = [&](size_t bytes) {
    void* p = ws + ob;
    ob = (ob + bytes + 255) & ~(size_t)255;
    return p;
  };
  float* y = (float*)alloc((size_t)N * DH * 4);
  int* cnt = (int*)alloc((size_t)N * R_ET * 4);
  int* offs = (int*)alloc((size_t)(N + 1) * 4);
  int* cursor = (int*)alloc((size_t)N * 4);
  int* bsum = (int*)alloc(1024 * 4);
  int2* meta = (int2*)alloc((size_t)E * 8);
  float* u = (float*)alloc(1024);
  ushort* Abf = (ushort*)alloc((size_t)Npad * DH * 2);
  ushort* Wt = (ushort*)alloc((size_t)3 * 9 * DH * DH * 2);
  ushort* tbuf = (ushort*)alloc((size_t)R_ET * N * DH * 2);
  (void)ws_size;

  hipMemsetAsync(u, 0, 2 * DH * sizeof(float), stream);
  for (int l = 0; l < 3; l++)
    wconv_kernel<<<9, 256, 0, stream>>>(rootp[l], Wp[l], Wt + (size_t)l * 9 * DH * DH);

  dim3 ggrid(Npad / 128, 3);
  dim3 egrid((E + 255) / 256);
  dim3 ngrid((N + 3) / 4);
  const int total = N * DH, padtotal = Npad * DH;
  dim3 agrid((padtotal / 4 + 255) / 256);

  for (int g = 0; g < 2; g++) {
    hipMemsetAsync(cnt, 0, (size_t)N * R_ET * sizeof(int), stream);
    count_kernel<<<egrid, 256, 0, stream>>>(ei[g], et[g], cnt, E);
    scan1_kernel<<<NB, 1024, 0, stream>>>(cnt, offs, bsum, N);
    scan2_kernel<<<1, 1024, 0, stream>>>(bsum, NB);
    scan3_kernel<<<NB, 1024, 0, stream>>>(offs, cursor, bsum, N, E);
    place_kernel<<<egrid, 256, 0, stream>>>(ei[g], et[g], cnt, cursor, meta, E);
    aconv_kernel<<<agrid, 256, 0, stream>>>(x[g], Abf, total, padtotal);
    for (int l = 0; l < 3; l++) {
      gemm_mfma<<<ggrid, 256, 0, stream>>>(Abf, Wt + (size_t)l * 9 * DH * DH,
                                           biasp[l], y, tbuf, N);
      if (l < 2) {
        gather_mid<<<ngrid, 256, 0, stream>>>(offs, meta, tbuf, y, Abf, N);
      } else {
        gather_last<<<ngrid, 256, 0, stream>>>(offs, meta, tbuf, y, N);
      }
    }
    pool_kernel<<<(N + 99) / 100, 256, 0, stream>>>(y, u + g * DH, N);
  }
  mlp_kernel<<<1, 256, 0, stream>>>(u, fc1w, fc1b, fc2w, fc2b, (float*)d_out, N);
}